// Round 1
// baseline (917.537 us; speedup 1.0000x reference)
//
#include <hip/hip_runtime.h>
#include <math.h>

#define V_N 8192
#define D_F 128
#define E_N 262144
#define K_N 512
#define DMAXF 0.5f
#define EPSW 1e-8f
#define EPSL 1e-5f

// ---------- transpose pmat (K x V) -> PT (V x K) ----------
__global__ __launch_bounds__(256) void k_transpose(const float* __restrict__ P, float* __restrict__ PT) {
  __shared__ float tile[32][33];
  int v0 = blockIdx.x * 32, k0 = blockIdx.y * 32;
  int tx = threadIdx.x, ty = threadIdx.y;
#pragma unroll
  for (int i = 0; i < 4; ++i)
    tile[ty + i * 8][tx] = P[(size_t)(k0 + ty + i * 8) * V_N + v0 + tx];
  __syncthreads();
#pragma unroll
  for (int i = 0; i < 4; ++i)
    PT[(size_t)(v0 + ty + i * 8) * K_N + k0 + tx] = tile[tx][ty + i * 8];
}

// ---------- per-edge weight, degree accumulation, strong-edge compaction ----------
__global__ __launch_bounds__(256) void k_edge(const float* __restrict__ X, const int* __restrict__ ei,
                                              float* __restrict__ deg, int* __restrict__ cnt,
                                              int* __restrict__ si, int* __restrict__ sj,
                                              float* __restrict__ sw) {
  int t = blockIdx.x * 256 + threadIdx.x;
  int e = t >> 4, lane = t & 15;           // 16 lanes per edge
  int i = ei[e], j = ei[E_N + e];
  const float4* xi = (const float4*)(X + (size_t)i * D_F);
  const float4* xj = (const float4*)(X + (size_t)j * D_F);
  float4 a0 = xi[lane * 2], a1 = xi[lane * 2 + 1];
  float4 b0 = xj[lane * 2], b1 = xj[lane * 2 + 1];
  float d = 0.f, dx;
  dx = a0.x - b0.x; d += dx * dx;
  dx = a0.y - b0.y; d += dx * dx;
  dx = a0.z - b0.z; d += dx * dx;
  dx = a0.w - b0.w; d += dx * dx;
  dx = a1.x - b1.x; d += dx * dx;
  dx = a1.y - b1.y; d += dx * dx;
  dx = a1.z - b1.z; d += dx * dx;
  dx = a1.w - b1.w; d += dx * dx;
  d += __shfl_xor(d, 1);
  d += __shfl_xor(d, 2);
  d += __shfl_xor(d, 4);
  d += __shfl_xor(d, 8);
  if (lane == 0) {
    bool strong = (d <= DMAXF);
    float w = strong ? expf(-d) : EPSW;
    atomicAdd(&deg[i], w);
    atomicAdd(&deg[j], w);
    if (strong) {
      int p = atomicAdd(cnt, 1);
      si[p] = i; sj[p] = j; sw[p] = w;
    }
  }
}

// ---------- scatter strong edges: Y[i] -= w*PT[j], Y[j] -= w*PT[i] ----------
__global__ __launch_bounds__(128) void k_scatter(const int* __restrict__ cnt, const int* __restrict__ si,
                                                 const int* __restrict__ sj, const float* __restrict__ sw,
                                                 const float* __restrict__ PT, float* __restrict__ Y) {
  int m = *cnt;
  int k0 = threadIdx.x * 4;                 // 128 threads cover 512 cols
  for (int e = blockIdx.x; e < m; e += gridDim.x) {
    int i = si[e], j = sj[e];
    float w = sw[e];
    float4 pj = *(const float4*)&PT[(size_t)j * K_N + k0];
    float4 pi = *(const float4*)&PT[(size_t)i * K_N + k0];
    float* yi = &Y[(size_t)i * K_N + k0];
    float* yj = &Y[(size_t)j * K_N + k0];
    atomicAdd(yi + 0, -w * pj.x); atomicAdd(yi + 1, -w * pj.y);
    atomicAdd(yi + 2, -w * pj.z); atomicAdd(yi + 3, -w * pj.w);
    atomicAdd(yj + 0, -w * pi.x); atomicAdd(yj + 1, -w * pi.y);
    atomicAdd(yj + 2, -w * pi.z); atomicAdd(yj + 3, -w * pi.w);
  }
}

// ---------- init L_adj = eps * I ----------
__global__ __launch_bounds__(256) void k_init(float* __restrict__ La) {
  int idx = blockIdx.x * 256 + threadIdx.x;
  La[idx] = ((idx >> 9) == (idx & 511)) ? EPSL : 0.f;
}

// ---------- L_adj += P @ (deg .* PT + Y), split-K over V ----------
#define GT_K 16
__global__ __launch_bounds__(256) void k_gemm(const float* __restrict__ P, const float* __restrict__ PT,
                                              const float* __restrict__ Y, const float* __restrict__ deg,
                                              float* __restrict__ La) {
  __shared__ float As[GT_K][68];   // As[k][r]
  __shared__ float Bs[GT_K][68];   // Bs[k][c]
  int a0 = blockIdx.x * 64, b0 = blockIdx.y * 64;
  int v0 = blockIdx.z * 1024;
  int tid = threadIdx.x;
  int rt = tid >> 4, ct = tid & 15;
  int r0 = rt * 4, c0 = ct * 4;
  float acc[4][4];
#pragma unroll
  for (int i = 0; i < 4; ++i)
#pragma unroll
    for (int j = 0; j < 4; ++j) acc[i][j] = 0.f;

  for (int kc = 0; kc < 1024; kc += GT_K) {
    { // load A tile (64 rows x 16 k), store transposed
      int r = tid >> 2, kq = (tid & 3) * 4;
      float4 f = *(const float4*)&P[(size_t)(a0 + r) * V_N + v0 + kc + kq];
      As[kq + 0][r] = f.x; As[kq + 1][r] = f.y; As[kq + 2][r] = f.z; As[kq + 3][r] = f.w;
    }
    { // load B tile (16 k x 64 cols), B = deg*PT + Y
      int k = tid >> 4, cq = (tid & 15) * 4;
      int v = v0 + kc + k;
      float4 fy = *(const float4*)&Y[(size_t)v * K_N + b0 + cq];
      float4 fp = *(const float4*)&PT[(size_t)v * K_N + b0 + cq];
      float dv = deg[v];
      float4 b;
      b.x = fy.x + dv * fp.x; b.y = fy.y + dv * fp.y;
      b.z = fy.z + dv * fp.z; b.w = fy.w + dv * fp.w;
      *(float4*)&Bs[k][cq] = b;
    }
    __syncthreads();
#pragma unroll
    for (int k = 0; k < GT_K; ++k) {
      float4 av = *(const float4*)&As[k][r0];
      float4 bv = *(const float4*)&Bs[k][c0];
      acc[0][0] += av.x * bv.x; acc[0][1] += av.x * bv.y; acc[0][2] += av.x * bv.z; acc[0][3] += av.x * bv.w;
      acc[1][0] += av.y * bv.x; acc[1][1] += av.y * bv.y; acc[1][2] += av.y * bv.z; acc[1][3] += av.y * bv.w;
      acc[2][0] += av.z * bv.x; acc[2][1] += av.z * bv.y; acc[2][2] += av.z * bv.z; acc[2][3] += av.z * bv.w;
      acc[3][0] += av.w * bv.x; acc[3][1] += av.w * bv.y; acc[3][2] += av.w * bv.z; acc[3][3] += av.w * bv.w;
    }
    __syncthreads();
  }
#pragma unroll
  for (int i = 0; i < 4; ++i)
#pragma unroll
    for (int j = 0; j < 4; ++j)
      atomicAdd(&La[(size_t)(a0 + r0 + i) * K_N + b0 + c0 + j], acc[i][j]);
}

// ---------- trace = sum(L_adj * targets^T) ----------
__global__ __launch_bounds__(256) void k_trace(const float* __restrict__ La, const float* __restrict__ T,
                                               float* __restrict__ tr) {
  int idx = blockIdx.x * 256 + threadIdx.x;
  float v = La[idx] * T[(size_t)(idx & 511) * K_N + (idx >> 9)];
  v += __shfl_down(v, 32); v += __shfl_down(v, 16); v += __shfl_down(v, 8);
  v += __shfl_down(v, 4);  v += __shfl_down(v, 2);  v += __shfl_down(v, 1);
  if ((threadIdx.x & 63) == 0) atomicAdd(tr, v);
}

// ---------- single-workgroup blocked Cholesky logdet (block 0: La in-place; block 1: targets -> Lw1) ----------
__global__ __launch_bounds__(1024) void k_chol(float* La, const float* T, float* Lw1, float* ld) {
  float* dst = (blockIdx.x == 0) ? La : Lw1;
  const float* src = (blockIdx.x == 0) ? (const float*)La : T;
  __shared__ float panel[K_N][33];   // 67.5 KB
  __shared__ float histT[32][36];    // 4.6 KB
  int tid = threadIdx.x;
  float logacc = 0.f;
  int rt = tid >> 3, ct = tid & 7;
  int r0 = rt << 2, c0 = ct << 2;

  for (int pb = 0; pb < K_N / 32; ++pb) {
    int j0 = pb * 32;
    int rows = K_N - j0;
    // load panel (rows x 32) from src
    for (int idx = tid; idx < rows * 32; idx += 1024) {
      int r = idx >> 5, c = idx & 31;
      panel[r][c] = src[(size_t)(j0 + r) * K_N + j0 + c];
    }
    __syncthreads();

    // history update: panel -= L[j0+r, :j0] @ L[j0+c, :j0]^T  (4x4 register tiles)
    int nslots = (rows >> 2) << 3;
    float acc[4][4];
#pragma unroll
    for (int i = 0; i < 4; ++i)
#pragma unroll
      for (int jj = 0; jj < 4; ++jj) acc[i][jj] = 0.f;

    for (int kb = 0; kb < pb; ++kb) {
      { int c = tid >> 5, k = tid & 31;
        histT[k][c] = dst[(size_t)(j0 + c) * K_N + kb * 32 + k]; }
      __syncthreads();
      if (tid < nslots) {
        const float* arow = &dst[(size_t)(j0 + r0) * K_N + kb * 32];
#pragma unroll
        for (int kk = 0; kk < 32; kk += 4) {
          float av[4][4];
#pragma unroll
          for (int i = 0; i < 4; ++i) {
            float4 f = *(const float4*)(arow + (size_t)i * K_N + kk);
            av[i][0] = f.x; av[i][1] = f.y; av[i][2] = f.z; av[i][3] = f.w;
          }
#pragma unroll
          for (int t = 0; t < 4; ++t) {
            float4 b = *(const float4*)&histT[kk + t][c0];
#pragma unroll
            for (int i = 0; i < 4; ++i) {
              acc[i][0] += av[i][t] * b.x;
              acc[i][1] += av[i][t] * b.y;
              acc[i][2] += av[i][t] * b.z;
              acc[i][3] += av[i][t] * b.w;
            }
          }
        }
      }
      __syncthreads();
    }
    if (pb > 0 && tid < nslots) {
#pragma unroll
      for (int i = 0; i < 4; ++i)
#pragma unroll
        for (int jj = 0; jj < 4; ++jj)
          panel[r0 + i][c0 + jj] -= acc[i][jj];
    }
    __syncthreads();

    // factor 32x32 diag block in-register by wave 0 (barrier-free, shfl-based)
    if (tid < 64) {
      int r = tid & 31;
      float a[32];
#pragma unroll
      for (int c = 0; c < 32; ++c) a[c] = panel[r][c];
      float ls = 0.f;
#pragma unroll
      for (int c = 0; c < 32; ++c) {
        float dc = __shfl(a[c], c);      // fully-updated diagonal (= L_cc^2)
        ls += logf(dc);
        float s = sqrtf(dc);
        a[c] = a[c] / s;                 // scale column c
#pragma unroll
        for (int k = c + 1; k < 32; ++k)
          a[k] -= a[c] * __shfl(a[c], k);
      }
      if (tid < 32) {
#pragma unroll
        for (int c = 0; c < 32; ++c) panel[r][c] = a[c];
      }
      if (tid == 0) logacc += ls;
    }
    __syncthreads();

    // TRSM: rows 32..rows-1, row-parallel forward substitution (barrier-free)
    {
      int r = 32 + tid;
      if (r < rows) {
        float x[32];
#pragma unroll
        for (int c = 0; c < 32; ++c) x[c] = panel[r][c];
#pragma unroll
        for (int c = 0; c < 32; ++c) {
          x[c] = x[c] / panel[c][c];
#pragma unroll
          for (int k = c + 1; k < 32; ++k)
            x[k] -= x[c] * panel[k][c];
        }
#pragma unroll
        for (int c = 0; c < 32; ++c) panel[r][c] = x[c];
      }
    }
    __syncthreads();

    // write panel back
    for (int idx = tid; idx < rows * 32; idx += 1024) {
      int r = idx >> 5, c = idx & 31;
      dst[(size_t)(j0 + r) * K_N + j0 + c] = panel[r][c];
    }
    __syncthreads();
  }
  if (tid == 0) ld[blockIdx.x] = logacc;
}

// ---------- combine ----------
__global__ void k_combine(const float* __restrict__ ld, const float* __restrict__ tr, float* __restrict__ out) {
  out[0] = -ld[0] - ld[1] - (float)K_N + tr[0];
}

extern "C" void kernel_launch(void* const* d_in, const int* in_sizes, int n_in,
                              void* d_out, int out_size, void* d_ws, size_t ws_size,
                              hipStream_t stream) {
  const float* X  = (const float*)d_in[0];   // inputs  [V,128]
  const float* T  = (const float*)d_in[1];   // targets [K,K]
  const int*   ei = (const int*)d_in[2];     // edge_index [2,E]
  const float* P  = (const float*)d_in[3];   // pmat [K,V]
  float* out = (float*)d_out;
  char* ws = (char*)d_ws;

  // workspace layout (bytes)
  int*   cnt = (int*)(ws + 0);
  float* tr  = (float*)(ws + 16);
  float* ld  = (float*)(ws + 32);
  float* deg = (float*)(ws + 256);                  // V floats
  float* PT  = (float*)(ws + 33024);                // V*K floats (16 MB)
  float* Y   = (float*)(ws + 16810240);             // V*K floats (16 MB)
  int*   si  = (int*)(ws + 33587456);               // E ints
  int*   sj  = (int*)(ws + 34636032);               // E ints
  float* sw  = (float*)(ws + 35684608);             // E floats
  float* La  = (float*)(ws + 36733184);             // K*K floats
  float* Lw1 = Y;                                   // reuse Y region (dead after GEMM) for targets' L

  hipMemsetAsync(ws, 0, 33024, stream);                       // cnt, tr, ld, deg
  hipMemsetAsync(Y, 0, (size_t)V_N * K_N * sizeof(float), stream);

  k_transpose<<<dim3(V_N / 32, K_N / 32), dim3(32, 8), 0, stream>>>(P, PT);
  k_edge<<<E_N / 16, 256, 0, stream>>>(X, ei, deg, cnt, si, sj, sw);
  k_scatter<<<2048, 128, 0, stream>>>(cnt, si, sj, sw, PT, Y);
  k_init<<<K_N * K_N / 256, 256, 0, stream>>>(La);
  k_gemm<<<dim3(8, 8, 8), 256, 0, stream>>>(P, PT, Y, deg, La);
  k_trace<<<K_N * K_N / 256, 256, 0, stream>>>(La, T, tr);
  k_chol<<<2, 1024, 0, stream>>>(La, T, Lw1, ld);
  k_combine<<<1, 1, 0, stream>>>(ld, tr, out);
}